// Round 11
// baseline (256.216 us; speedup 1.0000x reference)
//
#include <hip/hip_runtime.h>
#include <math.h>

#define NN 4096
#define DD 1024
#define M_TOT 32768
#define H1 512
#define MIN_ACTIVE 819
#define MARGIN 0.03f
#define MAXFIX 8192

typedef __bf16 bf16x8 __attribute__((ext_vector_type(8)));
typedef float f32x4 __attribute__((ext_vector_type(4)));

__device__ __forceinline__ unsigned short f2bf(float f) {
    unsigned int u = __float_as_uint(f);
    return (unsigned short)((u + 0x7FFFu + ((u >> 16) & 1u)) >> 16);
}

__device__ __forceinline__ void glds16(const unsigned short* g, unsigned short* l) {
    __builtin_amdgcn_global_load_lds(
        (const __attribute__((address_space(1))) unsigned int*)g,
        (__attribute__((address_space(3))) unsigned int*)l, 16, 0, 0);
}

// ---------------- K1: pre1 = convB repack (blk 0-255) + pmean (blk 256-511) + zero counters ----------------
__global__ void pre1_kernel(const float* __restrict__ w1, unsigned short* __restrict__ w1tt,
                            const float* __restrict__ ctx, float* __restrict__ pmean,
                            const unsigned char* __restrict__ rare, int* __restrict__ mode,
                            int* __restrict__ fixcnt, unsigned int* __restrict__ rowcnt,
                            int* __restrict__ syncA, int* __restrict__ syncB) {
    __shared__ float tile[32][65];
    __shared__ int nonbin, oneoff;
    int blk = blockIdx.x;
    int tid = threadIdx.x;
    // zero 64 rowcnt entries per block (32768 over 512 blocks)
    if (tid < 64) rowcnt[blk * 64 + tid] = 0u;
    if (blk == 0 && tid == 0) { *fixcnt = 0; *syncA = 0; *syncB = 0; }
    if (blk < 256) {
        int t = blk >> 3;            // k-tile 0..31
        int c0 = (blk & 7) * 64;     // col group
        #pragma unroll
        for (int i = 0; i < 8; ++i) {
            int idx = tid + 256 * i;
            int kk = idx >> 6, cc = idx & 63;
            tile[kk][cc] = w1[(size_t)(t * 32 + kk) * H1 + c0 + cc];
        }
        __syncthreads();
        {
            int cc = tid >> 2, jp = tid & 3;
            int c = c0 + cc;
            int j = jp ^ ((c >> 1) & 3);
            unsigned int w[4];
            #pragma unroll
            for (int q = 0; q < 4; ++q)
                w[q] = (unsigned int)f2bf(tile[j * 8 + 2 * q][cc])
                     | ((unsigned int)f2bf(tile[j * 8 + 2 * q + 1][cc]) << 16);
            uint4 v; v.x = w[0]; v.y = w[1]; v.z = w[2]; v.w = w[3];
            *(uint4*)(w1tt + ((size_t)t * 512 + c) * 32 + jp * 8) = v;
        }
        if (blk == 0) {
            if (tid == 0) { nonbin = 0; oneoff = 0; }
            __syncthreads();
            int lnon = 0, lone = 0;
            for (int i = tid; i < 32768; i += 256) {
                unsigned char b = rare[i];
                if (b > 1) lnon = 1;
                else if (b == 1 && (i & 3) != 0) lone = 1;
            }
            if (lnon) atomicOr(&nonbin, 1);
            if (lone) atomicOr(&oneoff, 1);
            __syncthreads();
            if (tid == 0) *mode = nonbin ? 2 : (oneoff ? 1 : 0);
        }
    } else {
        int pblk = blk - 256;        // 256 = 8b * 4dq * 8nz
        int b = pblk >> 5, dq = (pblk >> 3) & 3, nz = pblk & 7;
        int d = dq * 256 + tid;
        const float* base = ctx + ((size_t)(b * 512 + nz * 64)) * DD + d;
        float acc = 0.f;
        for (int n = 0; n < 64; ++n) acc += base[(size_t)n * DD];
        pmean[(b * 8 + nz) * DD + d] = acc;
    }
}

// ---------------- K2: pre2 = midk (ctx_bn blk 0-63, t_emb blk 64-191) + spin-sync + baseh (blk 0-127) ----------------
__global__ __launch_bounds__(256) void pre2_kernel(
    const float* __restrict__ pmean, const int* __restrict__ t,
    const float* __restrict__ ctx_w, const float* __restrict__ ctx_b,
    const float* __restrict__ tpw, const float* __restrict__ tpb,
    const float* __restrict__ w1, const float* __restrict__ b1,
    float* __restrict__ ctx_bn, float* __restrict__ t_emb,
    float* __restrict__ base_h, int* __restrict__ syncA) {
    __shared__ float sh[1024];
    __shared__ float red8[8][32];
    __shared__ float red4[4][64];
    int tid = threadIdx.x;
    int blk = blockIdx.x;
    if (blk < 64) {
        int b = blk >> 3, cg = blk & 7;
        for (int j = tid; j < 1024; j += 256) {
            float s = 0.f;
            #pragma unroll
            for (int nz = 0; nz < 8; ++nz) s += pmean[(b * 8 + nz) * DD + j];
            sh[j] = s * (1.f / 512.f);
        }
        __syncthreads();
        int c = cg * 32 + (tid & 31), ks = tid >> 5;
        const float* mb = sh + ks * 128;
        const float* wb = ctx_w + (size_t)(ks * 128) * 256 + c;
        float acc = 0.f;
        for (int i = 0; i < 128; ++i) acc += mb[i] * wb[(size_t)i * 256];
        red8[ks][tid & 31] = acc;
        __syncthreads();
        if (tid < 32) {
            float s = 0.f;
            for (int k = 0; k < 8; ++k) s += red8[k][tid];
            ctx_bn[b * 256 + cg * 32 + tid] = s + ctx_b[cg * 32 + tid];
        }
    } else {
        int bb = blk - 64;
        int b = bb >> 4, cg = bb & 15;
        double tv = (double)t[b];
        const double neg_ln = -log(10000.0) / 511.0;
        for (int j = tid; j < 1024; j += 256) {
            int jj = j & 511;
            double arg = tv * exp(neg_ln * (double)jj);
            sh[j] = (float)((j < 512) ? sin(arg) : cos(arg));
        }
        __syncthreads();
        int c = cg * 64 + (tid & 63), ks = tid >> 6;
        const float* eb = sh + ks * 256;
        const float* wb = tpw + (size_t)(ks * 256) * DD + c;
        float acc = 0.f;
        for (int i = 0; i < 256; ++i) acc += eb[i] * wb[(size_t)i * DD];
        red4[ks][tid & 63] = acc;
        __syncthreads();
        if (tid < 64) {
            float s = red4[0][tid] + red4[1][tid] + red4[2][tid] + red4[3][tid];
            t_emb[b * DD + cg * 64 + tid] = s + tpb[cg * 64 + tid];
        }
    }
    // arrive (release)
    __syncthreads();
    __threadfence();
    if (tid == 0) atomicAdd(syncA, 1);
    // baseh on blocks 0-127 after all 192 arrived (acquire)
    if (blk < 128) {
        if (tid == 0) {
            while (atomicAdd(syncA, 0) < 192) __builtin_amdgcn_s_sleep(8);
        }
        __syncthreads();
        __threadfence();
        __shared__ float red[8][32];
        int b = blk >> 4, cg = blk & 15;
        int c = cg * 32 + (tid & 31), ks = tid >> 5;
        float acc = 0.f;
        for (int i = 0; i < 160; ++i) {
            int k = ks * 160 + i;
            float v = (k < 256) ? ctx_bn[b * 256 + k] : t_emb[b * DD + k - 256];
            acc += v * w1[(size_t)(1024 + k) * H1 + c];
        }
        red[ks][tid & 31] = acc;
        __syncthreads();
        if (tid < 32) {
            float s = 0.f;
            for (int k = 0; k < 8; ++k) s += red[k][tid];
            base_h[b * H1 + cg * 32 + tid] = s + b1[cg * 32 + tid];
        }
    }
}

// ---------------- K3: MFMA GEMM (r9 config) + fused score via per-row two-arrival protocol ----------------
__global__ __launch_bounds__(512, 4) void gemm_kernel(
    const float* __restrict__ tokens, const unsigned short* __restrict__ w1tt,
    const float* __restrict__ baseh, const float* __restrict__ w2,
    const float* __restrict__ b2, const void* __restrict__ rare,
    const int* __restrict__ mode_p, float* __restrict__ out,
    int* __restrict__ fixcnt, int* __restrict__ fixlist,
    float* __restrict__ part, unsigned int* __restrict__ rowcnt) {
    __shared__ unsigned short As[2][128 * 40];
    __shared__ unsigned short Bs[3][256 * 32];
    __shared__ float red[128][4];
    int tid = threadIdx.x;
    int lane = tid & 63, wid = tid >> 6;
    int wm = wid >> 2, wn = wid & 3;
    int la = lane & 15, lk = lane >> 4;
    int row0 = blockIdx.x * 128;
    int half = blockIdx.y;
    const unsigned short* wsrc = w1tt + (size_t)half * 256 * 32;

    f32x4 acc[4][4];
    #pragma unroll
    for (int i = 0; i < 4; ++i)
        #pragma unroll
        for (int j = 0; j < 4; ++j)
            acc[i][j] = (f32x4){0.f, 0.f, 0.f, 0.f};

    float4 sa0[2], sa1[2];
    #define LOAD_A(kt_, S_) { \
        _Pragma("unroll") \
        for (int i = 0; i < 2; ++i) { \
            int id = tid + 512 * i; \
            int r = id >> 3, xk = id & 7; \
            S_[i] = *(const float4*)(tokens + (size_t)(row0 + r) * DD + (kt_) + xk * 4); \
        } }
    #define WRITE_A(bb_, S_) { \
        _Pragma("unroll") \
        for (int i = 0; i < 2; ++i) { \
            int id = tid + 512 * i; \
            int r = id >> 3, xk = id & 7; \
            ushort4 h; \
            h.x = f2bf(S_[i].x); h.y = f2bf(S_[i].y); \
            h.z = f2bf(S_[i].z); h.w = f2bf(S_[i].w); \
            *(ushort4*)(&As[bb_][r * 40 + xk * 4]) = h; \
        } }
    #define STAGE_B(t_, bb_) { \
        const unsigned short* gsrc = wsrc + (size_t)(t_) * 512 * 32; \
        _Pragma("unroll") \
        for (int q = 0; q < 2; ++q) { \
            int chunk = wid * 2 + q; \
            glds16(gsrc + chunk * 512 + lane * 8, &Bs[bb_][chunk * 512]); \
        } }

    LOAD_A(0, sa0);
    STAGE_B(0, 0);
    STAGE_B(1, 1);
    WRITE_A(0, sa0);
    LOAD_A(32, sa1);
    __builtin_amdgcn_sched_barrier(0);
    asm volatile("s_waitcnt vmcnt(4)" ::: "memory");
    asm volatile("s_waitcnt lgkmcnt(0)" ::: "memory");
    __builtin_amdgcn_s_barrier();
    __builtin_amdgcn_sched_barrier(0);

    for (int t = 0; t < 32; ++t) {
        int bb = t & 1;
        const unsigned short* bsrc = Bs[t % 3];
        bf16x8 af[4], bfr[4];
        #pragma unroll
        for (int mf = 0; mf < 4; ++mf) {
            int r = wm * 64 + mf * 16 + la;
            af[mf] = *(const bf16x8*)(&As[bb][r * 40 + lk * 8]);
        }
        #pragma unroll
        for (int nf = 0; nf < 4; ++nf) {
            int c = wn * 64 + nf * 16 + la;
            int sw = lk ^ ((c >> 1) & 3);
            bfr[nf] = *(const bf16x8*)(&bsrc[c * 32 + sw * 8]);
        }
        __builtin_amdgcn_s_setprio(1);
        #pragma unroll
        for (int mf = 0; mf < 4; ++mf)
            #pragma unroll
            for (int nf = 0; nf < 4; ++nf)
                acc[mf][nf] = __builtin_amdgcn_mfma_f32_16x16x32_bf16(af[mf], bfr[nf], acc[mf][nf], 0, 0, 0);
        __builtin_amdgcn_s_setprio(0);
        __builtin_amdgcn_sched_barrier(0);
        if (t < 31) {
            if (t & 1) { WRITE_A(bb ^ 1, sa0) } else { WRITE_A(bb ^ 1, sa1) }
            if (t < 30) {
                if (t & 1) { LOAD_A((t + 2) * 32, sa1) } else { LOAD_A((t + 2) * 32, sa0) }
                STAGE_B(t + 2, (t + 2) % 3);
            }
            __builtin_amdgcn_sched_barrier(0);
            if (t < 30) asm volatile("s_waitcnt vmcnt(4)" ::: "memory");
            else        asm volatile("s_waitcnt vmcnt(0)" ::: "memory");
            asm volatile("s_waitcnt lgkmcnt(0)" ::: "memory");
            __builtin_amdgcn_s_barrier();
            __builtin_amdgcn_sched_barrier(0);
        }
    }
    #undef LOAD_A
    #undef WRITE_A
    #undef STAGE_B

    int b = row0 >> 12;
    const float* bh = baseh + b * H1;
    float bhv[4], w2v[4];
    #pragma unroll
    for (int nf = 0; nf < 4; ++nf) {
        int col = half * 256 + wn * 64 + nf * 16 + la;
        bhv[nf] = bh[col];
        w2v[nf] = w2[col];
    }
    #pragma unroll
    for (int mf = 0; mf < 4; ++mf) {
        #pragma unroll
        for (int reg = 0; reg < 4; ++reg) {
            float p = 0.f;
            #pragma unroll
            for (int nf = 0; nf < 4; ++nf) {
                float h = acc[mf][nf][reg] + bhv[nf];
                h = fmaxf(h, 0.f);
                p += h * w2v[nf];
            }
            p += __shfl_xor(p, 1, 64);
            p += __shfl_xor(p, 2, 64);
            p += __shfl_xor(p, 4, 64);
            p += __shfl_xor(p, 8, 64);
            if (la == 0) red[wm * 64 + mf * 16 + lk * 4 + reg][wn] = p;
        }
    }
    __syncthreads();
    if (tid < 128) {
        int row = row0 + tid;
        float pa = red[tid][0] + red[tid][1] + red[tid][2] + red[tid][3];
        part[(size_t)row * 2 + half] = pa;
        __threadfence();
        unsigned int old = atomicAdd(&rowcnt[row], 1u);
        if (old == 1u) {   // second arriver: other half's partial is visible
            __threadfence();
            float p0 = (half == 0) ? pa : part[(size_t)row * 2];
            float p1 = (half == 1) ? pa : part[(size_t)row * 2 + 1];
            float logit = p0 + p1 + b2[0];
            float score = 1.f / (1.f + expf(-logit));
            int mode = *mode_p;
            bool rm = (mode == 1) ? (((const unsigned char*)rare)[row] != 0)
                    : (mode == 2) ? (((const float*)rare)[row] != 0.f)
                    : (((const int*)rare)[row] != 0);
            out[row] = ((score > 0.5f) && !rm) ? 1.f : 0.f;
            out[M_TOT + row] = score;
            if (fabsf(logit) < MARGIN) {
                int i = atomicAdd(fixcnt, 1);
                if (i < MAXFIX) fixlist[i] = row;
            }
        }
    }
}

// ---------------- K4: fixpost = fixup (all 256 blocks) + spin-sync + floor (blocks 0-7) ----------------
__global__ __launch_bounds__(512) void fixpost_kernel(
    const int* __restrict__ fixcnt, const int* __restrict__ fixlist,
    const float* __restrict__ tokens, const float* __restrict__ w1,
    const float* __restrict__ base_h, const float* __restrict__ w2,
    const float* __restrict__ b2, const void* __restrict__ rare,
    const int* __restrict__ mode_p, float* __restrict__ out,
    int* __restrict__ syncB) {
    __shared__ float tok[DD];
    __shared__ float part4[4][H1];
    __shared__ float red[8];
    __shared__ float s[NN];
    __shared__ unsigned char fl[NN];
    __shared__ int scnt;
    int tid = threadIdx.x;
    int lane = tid & 63, wid = tid >> 6;
    int ks = tid >> 7;
    int cg = tid & 127;
    int n = *fixcnt;
    if (n > MAXFIX) n = MAXFIX;
    for (int g = blockIdx.x; g < n; g += gridDim.x) {
        int row = fixlist[g];
        int b = row >> 12;
        if (tid < 256)
            ((float4*)tok)[tid] = ((const float4*)(tokens + (size_t)row * DD))[tid];
        __syncthreads();
        const float* wbase = w1 + (size_t)(ks * 256) * H1 + cg * 4;
        const float* tbase = tok + ks * 256;
        float4 a = {0.f, 0.f, 0.f, 0.f};
        #pragma unroll 8
        for (int k = 0; k < 256; ++k) {
            float4 w = *(const float4*)(wbase + (size_t)k * H1);
            float tv = tbase[k];
            a.x += tv * w.x; a.y += tv * w.y; a.z += tv * w.z; a.w += tv * w.w;
        }
        *(float4*)&part4[ks][cg * 4] = a;
        __syncthreads();
        float h = part4[0][tid] + part4[1][tid] + part4[2][tid] + part4[3][tid]
                + base_h[b * H1 + tid];
        h = fmaxf(h, 0.f);
        float p = h * w2[tid];
        p += __shfl_xor(p, 1, 64);
        p += __shfl_xor(p, 2, 64);
        p += __shfl_xor(p, 4, 64);
        p += __shfl_xor(p, 8, 64);
        p += __shfl_xor(p, 16, 64);
        p += __shfl_xor(p, 32, 64);
        if (lane == 0) red[wid] = p;
        __syncthreads();
        if (tid == 0) {
            float logit = b2[0];
            #pragma unroll
            for (int w = 0; w < 8; ++w) logit += red[w];
            float score = 1.f / (1.f + expf(-logit));
            int mode = *mode_p;
            bool rm = (mode == 1) ? (((const unsigned char*)rare)[row] != 0)
                    : (mode == 2) ? (((const float*)rare)[row] != 0.f)
                    : (((const int*)rare)[row] != 0);
            out[row] = ((score > 0.5f) && !rm) ? 1.f : 0.f;
            out[M_TOT + row] = score;
        }
        __syncthreads();
    }
    // arrive (release)
    __threadfence();
    __syncthreads();
    if (tid == 0) atomicAdd(syncB, 1);
    // floor on blocks 0-7 after all 256 arrived
    if (blockIdx.x < 8) {
        if (tid == 0) {
            while (atomicAdd(syncB, 0) < 256) __builtin_amdgcn_s_sleep(8);
        }
        __syncthreads();
        __threadfence();
        int b = blockIdx.x;
        if (tid == 0) scnt = 0;
        __syncthreads();
        int local = 0;
        for (int i = tid; i < NN; i += 512) {
            s[i] = out[M_TOT + b * NN + i];
            unsigned char sk = out[b * NN + i] > 0.5f;
            fl[i] = sk;
            local += sk;
        }
        atomicAdd(&scnt, local);
        __syncthreads();
        int deficit = scnt - (NN - MIN_ACTIVE);
        if (deficit <= 0) return;
        for (int i = tid; i < NN; i += 512) {
            if (!fl[i]) continue;
            float si = s[i];
            int rank = 0;
            for (int j = 0; j < NN; ++j) {
                if (fl[j] && (s[j] < si || (s[j] == si && j < i))) {
                    if (++rank >= deficit) break;
                }
            }
            if (rank < deficit) out[b * NN + i] = 0.f;
        }
    }
}

extern "C" void kernel_launch(void* const* d_in, const int* in_sizes, int n_in,
                              void* d_out, int out_size, void* d_ws, size_t ws_size,
                              hipStream_t stream) {
    const float* tokens   = (const float*)d_in[0];
    const float* ctx_C    = (const float*)d_in[1];
    const int*   t        = (const int*)d_in[2];
    const void*  rare     = d_in[3];
    const float* ctx_w    = (const float*)d_in[4];
    const float* ctx_b    = (const float*)d_in[5];
    const float* t_proj_w = (const float*)d_in[6];
    const float* t_proj_b = (const float*)d_in[7];
    const float* w1       = (const float*)d_in[8];
    const float* b1       = (const float*)d_in[9];
    const float* w2       = (const float*)d_in[10];
    const float* b2       = (const float*)d_in[11];
    float* out = (float*)d_out;

    char* ws = (char*)d_ws;
    unsigned short* w1tt  = (unsigned short*)(ws);                 // 1,048,576 B
    float* pmean          = (float*)(ws + 1048576);                // 262,144 B
    float* part           = (float*)(ws + 1310720);                // 262,144 B
    unsigned int* rowcnt  = (unsigned int*)(ws + 1572864);         // 131,072 B
    float* ctx_bn         = (float*)(ws + 1703936);                // 8,192 B
    float* t_emb          = (float*)(ws + 1712128);                // 32,768 B
    float* base_h         = (float*)(ws + 1744896);                // 16,384 B
    int*   mode           = (int*)  (ws + 1761280);                // 4 B
    int*   fixcnt         = (int*)  (ws + 1761344);                // 4 B
    int*   syncA          = (int*)  (ws + 1761408);                // 4 B
    int*   syncB          = (int*)  (ws + 1761472);                // 4 B
    int*   fixlist        = (int*)  (ws + 1761536);                // 32,768 B

    pre1_kernel<<<512, 256, 0, stream>>>(w1, w1tt, ctx_C, pmean,
                                         (const unsigned char*)rare, mode, fixcnt,
                                         rowcnt, syncA, syncB);
    pre2_kernel<<<192, 256, 0, stream>>>(pmean, t, ctx_w, ctx_b, t_proj_w, t_proj_b,
                                         w1, b1, ctx_bn, t_emb, base_h, syncA);
    gemm_kernel<<<dim3(256, 2), 512, 0, stream>>>(tokens, w1tt, base_h, w2, b2, rare,
                                                  mode, out, fixcnt, fixlist, part, rowcnt);
    fixpost_kernel<<<256, 512, 0, stream>>>(fixcnt, fixlist, tokens, w1, base_h, w2,
                                            b2, rare, mode, out, syncB);
}

// Round 12
// 234.946 us; speedup vs baseline: 1.0905x; 1.0905x over previous
//
#include <hip/hip_runtime.h>
#include <math.h>

#define NN 4096
#define DD 1024
#define M_TOT 32768
#define H1 512
#define MIN_ACTIVE 819
#define MARGIN 0.03f
#define MAXFIX 8192

typedef __bf16 bf16x8 __attribute__((ext_vector_type(8)));
typedef float f32x4 __attribute__((ext_vector_type(4)));

__device__ __forceinline__ unsigned short f2bf(float f) {
    unsigned int u = __float_as_uint(f);
    return (unsigned short)((u + 0x7FFFu + ((u >> 16) & 1u)) >> 16);
}

__device__ __forceinline__ void glds16(const unsigned short* g, unsigned short* l) {
    __builtin_amdgcn_global_load_lds(
        (const __attribute__((address_space(1))) unsigned int*)g,
        (__attribute__((address_space(3))) unsigned int*)l, 16, 0, 0);
}

// ---------------- K1: pre1 = convB repack (blk 0-255) + pmean (blk 256-511) + zero flags ----------------
__global__ void pre1_kernel(const float* __restrict__ w1, unsigned short* __restrict__ w1tt,
                            const float* __restrict__ ctx, float* __restrict__ pmean,
                            const unsigned char* __restrict__ rare, int* __restrict__ mode,
                            int* __restrict__ fixcnt, int* __restrict__ syncA,
                            int* __restrict__ syncB) {
    __shared__ float tile[32][65];
    __shared__ int nonbin, oneoff;
    int blk = blockIdx.x;
    int tid = threadIdx.x;
    if (blk == 0 && tid == 0) { *fixcnt = 0; *syncA = 0; *syncB = 0; }
    if (blk < 256) {
        int t = blk >> 3;            // k-tile 0..31
        int c0 = (blk & 7) * 64;     // col group
        #pragma unroll
        for (int i = 0; i < 8; ++i) {
            int idx = tid + 256 * i;
            int kk = idx >> 6, cc = idx & 63;
            tile[kk][cc] = w1[(size_t)(t * 32 + kk) * H1 + c0 + cc];
        }
        __syncthreads();
        {
            int cc = tid >> 2, jp = tid & 3;
            int c = c0 + cc;
            int j = jp ^ ((c >> 1) & 3);
            unsigned int w[4];
            #pragma unroll
            for (int q = 0; q < 4; ++q)
                w[q] = (unsigned int)f2bf(tile[j * 8 + 2 * q][cc])
                     | ((unsigned int)f2bf(tile[j * 8 + 2 * q + 1][cc]) << 16);
            uint4 v; v.x = w[0]; v.y = w[1]; v.z = w[2]; v.w = w[3];
            *(uint4*)(w1tt + ((size_t)t * 512 + c) * 32 + jp * 8) = v;
        }
        if (blk == 0) {
            if (tid == 0) { nonbin = 0; oneoff = 0; }
            __syncthreads();
            int lnon = 0, lone = 0;
            for (int i = tid; i < 32768; i += 256) {
                unsigned char b = rare[i];
                if (b > 1) lnon = 1;
                else if (b == 1 && (i & 3) != 0) lone = 1;
            }
            if (lnon) atomicOr(&nonbin, 1);
            if (lone) atomicOr(&oneoff, 1);
            __syncthreads();
            if (tid == 0) *mode = nonbin ? 2 : (oneoff ? 1 : 0);
        }
    } else {
        int pblk = blk - 256;        // 256 = 8b * 4dq * 8nz
        int b = pblk >> 5, dq = (pblk >> 3) & 3, nz = pblk & 7;
        int d = dq * 256 + tid;
        const float* base = ctx + ((size_t)(b * 512 + nz * 64)) * DD + d;
        float acc = 0.f;
        for (int n = 0; n < 64; ++n) acc += base[(size_t)n * DD];
        pmean[(b * 8 + nz) * DD + d] = acc;
    }
}

// ---------------- K2: pre2 = midk (ctx_bn blk 0-63, t_emb blk 64-191) + spin-sync + baseh (blk 0-127) ----------------
__global__ __launch_bounds__(256) void pre2_kernel(
    const float* __restrict__ pmean, const int* __restrict__ t,
    const float* __restrict__ ctx_w, const float* __restrict__ ctx_b,
    const float* __restrict__ tpw, const float* __restrict__ tpb,
    const float* __restrict__ w1, const float* __restrict__ b1,
    float* __restrict__ ctx_bn, float* __restrict__ t_emb,
    float* __restrict__ base_h, int* __restrict__ syncA) {
    __shared__ float sh[1024];
    __shared__ float red8[8][32];
    __shared__ float red4[4][64];
    int tid = threadIdx.x;
    int blk = blockIdx.x;
    if (blk < 64) {
        int b = blk >> 3, cg = blk & 7;
        for (int j = tid; j < 1024; j += 256) {
            float s = 0.f;
            #pragma unroll
            for (int nz = 0; nz < 8; ++nz) s += pmean[(b * 8 + nz) * DD + j];
            sh[j] = s * (1.f / 512.f);
        }
        __syncthreads();
        int c = cg * 32 + (tid & 31), ks = tid >> 5;
        const float* mb = sh + ks * 128;
        const float* wb = ctx_w + (size_t)(ks * 128) * 256 + c;
        float acc = 0.f;
        for (int i = 0; i < 128; ++i) acc += mb[i] * wb[(size_t)i * 256];
        red8[ks][tid & 31] = acc;
        __syncthreads();
        if (tid < 32) {
            float s = 0.f;
            for (int k = 0; k < 8; ++k) s += red8[k][tid];
            ctx_bn[b * 256 + cg * 32 + tid] = s + ctx_b[cg * 32 + tid];
        }
    } else {
        int bb = blk - 64;
        int b = bb >> 4, cg = bb & 15;
        double tv = (double)t[b];
        const double neg_ln = -log(10000.0) / 511.0;
        for (int j = tid; j < 1024; j += 256) {
            int jj = j & 511;
            double arg = tv * exp(neg_ln * (double)jj);
            sh[j] = (float)((j < 512) ? sin(arg) : cos(arg));
        }
        __syncthreads();
        int c = cg * 64 + (tid & 63), ks = tid >> 6;
        const float* eb = sh + ks * 256;
        const float* wb = tpw + (size_t)(ks * 256) * DD + c;
        float acc = 0.f;
        for (int i = 0; i < 256; ++i) acc += eb[i] * wb[(size_t)i * DD];
        red4[ks][tid & 63] = acc;
        __syncthreads();
        if (tid < 64) {
            float s = red4[0][tid] + red4[1][tid] + red4[2][tid] + red4[3][tid];
            t_emb[b * DD + cg * 64 + tid] = s + tpb[cg * 64 + tid];
        }
    }
    // arrive (release)
    __syncthreads();
    __threadfence();
    if (tid == 0) atomicAdd(syncA, 1);
    // baseh on blocks 0-127 after all 192 arrived (acquire)
    if (blk < 128) {
        if (tid == 0) {
            while (atomicAdd(syncA, 0) < 192) __builtin_amdgcn_s_sleep(8);
        }
        __syncthreads();
        __threadfence();
        __shared__ float red[8][32];
        int b = blk >> 4, cg = blk & 15;
        int c = cg * 32 + (tid & 31), ks = tid >> 5;
        float acc = 0.f;
        for (int i = 0; i < 160; ++i) {
            int k = ks * 160 + i;
            float v = (k < 256) ? ctx_bn[b * 256 + k] : t_emb[b * DD + k - 256];
            acc += v * w1[(size_t)(1024 + k) * H1 + c];
        }
        red[ks][tid & 31] = acc;
        __syncthreads();
        if (tid < 32) {
            float s = 0.f;
            for (int k = 0; k < 8; ++k) s += red[k][tid];
            base_h[b * H1 + cg * 32 + tid] = s + b1[cg * 32 + tid];
        }
    }
}

// ---------------- K3: MFMA GEMM (exact r9 config: MFMA-first, 3-buf B, dual A regs) ----------------
__global__ __launch_bounds__(512, 4) void gemm_kernel(
    const float* __restrict__ tokens, const unsigned short* __restrict__ w1tt,
    const float* __restrict__ baseh, const float* __restrict__ w2,
    float* __restrict__ part) {
    __shared__ unsigned short As[2][128 * 40];
    __shared__ unsigned short Bs[3][256 * 32];
    __shared__ float red[128][4];
    int tid = threadIdx.x;
    int lane = tid & 63, wid = tid >> 6;
    int wm = wid >> 2, wn = wid & 3;
    int la = lane & 15, lk = lane >> 4;
    int row0 = blockIdx.x * 128;
    int half = blockIdx.y;
    const unsigned short* wsrc = w1tt + (size_t)half * 256 * 32;

    f32x4 acc[4][4];
    #pragma unroll
    for (int i = 0; i < 4; ++i)
        #pragma unroll
        for (int j = 0; j < 4; ++j)
            acc[i][j] = (f32x4){0.f, 0.f, 0.f, 0.f};

    float4 sa0[2], sa1[2];
    #define LOAD_A(kt_, S_) { \
        _Pragma("unroll") \
        for (int i = 0; i < 2; ++i) { \
            int id = tid + 512 * i; \
            int r = id >> 3, xk = id & 7; \
            S_[i] = *(const float4*)(tokens + (size_t)(row0 + r) * DD + (kt_) + xk * 4); \
        } }
    #define WRITE_A(bb_, S_) { \
        _Pragma("unroll") \
        for (int i = 0; i < 2; ++i) { \
            int id = tid + 512 * i; \
            int r = id >> 3, xk = id & 7; \
            ushort4 h; \
            h.x = f2bf(S_[i].x); h.y = f2bf(S_[i].y); \
            h.z = f2bf(S_[i].z); h.w = f2bf(S_[i].w); \
            *(ushort4*)(&As[bb_][r * 40 + xk * 4]) = h; \
        } }
    #define STAGE_B(t_, bb_) { \
        const unsigned short* gsrc = wsrc + (size_t)(t_) * 512 * 32; \
        _Pragma("unroll") \
        for (int q = 0; q < 2; ++q) { \
            int chunk = wid * 2 + q; \
            glds16(gsrc + chunk * 512 + lane * 8, &Bs[bb_][chunk * 512]); \
        } }

    LOAD_A(0, sa0);
    STAGE_B(0, 0);
    STAGE_B(1, 1);
    WRITE_A(0, sa0);
    LOAD_A(32, sa1);
    __builtin_amdgcn_sched_barrier(0);
    asm volatile("s_waitcnt vmcnt(4)" ::: "memory");
    asm volatile("s_waitcnt lgkmcnt(0)" ::: "memory");
    __builtin_amdgcn_s_barrier();
    __builtin_amdgcn_sched_barrier(0);

    for (int t = 0; t < 32; ++t) {
        int bb = t & 1;
        const unsigned short* bsrc = Bs[t % 3];
        bf16x8 af[4], bfr[4];
        #pragma unroll
        for (int mf = 0; mf < 4; ++mf) {
            int r = wm * 64 + mf * 16 + la;
            af[mf] = *(const bf16x8*)(&As[bb][r * 40 + lk * 8]);
        }
        #pragma unroll
        for (int nf = 0; nf < 4; ++nf) {
            int c = wn * 64 + nf * 16 + la;
            int sw = lk ^ ((c >> 1) & 3);
            bfr[nf] = *(const bf16x8*)(&bsrc[c * 32 + sw * 8]);
        }
        __builtin_amdgcn_s_setprio(1);
        #pragma unroll
        for (int mf = 0; mf < 4; ++mf)
            #pragma unroll
            for (int nf = 0; nf < 4; ++nf)
                acc[mf][nf] = __builtin_amdgcn_mfma_f32_16x16x32_bf16(af[mf], bfr[nf], acc[mf][nf], 0, 0, 0);
        __builtin_amdgcn_s_setprio(0);
        __builtin_amdgcn_sched_barrier(0);
        if (t < 31) {
            if (t & 1) { WRITE_A(bb ^ 1, sa0) } else { WRITE_A(bb ^ 1, sa1) }
            if (t < 30) {
                if (t & 1) { LOAD_A((t + 2) * 32, sa1) } else { LOAD_A((t + 2) * 32, sa0) }
                STAGE_B(t + 2, (t + 2) % 3);
            }
            __builtin_amdgcn_sched_barrier(0);
            if (t < 30) asm volatile("s_waitcnt vmcnt(4)" ::: "memory");
            else        asm volatile("s_waitcnt vmcnt(0)" ::: "memory");
            asm volatile("s_waitcnt lgkmcnt(0)" ::: "memory");
            __builtin_amdgcn_s_barrier();
            __builtin_amdgcn_sched_barrier(0);
        }
    }
    #undef LOAD_A
    #undef WRITE_A
    #undef STAGE_B

    int b = row0 >> 12;
    const float* bh = baseh + b * H1;
    float bhv[4], w2v[4];
    #pragma unroll
    for (int nf = 0; nf < 4; ++nf) {
        int col = half * 256 + wn * 64 + nf * 16 + la;
        bhv[nf] = bh[col];
        w2v[nf] = w2[col];
    }
    #pragma unroll
    for (int mf = 0; mf < 4; ++mf) {
        #pragma unroll
        for (int reg = 0; reg < 4; ++reg) {
            float p = 0.f;
            #pragma unroll
            for (int nf = 0; nf < 4; ++nf) {
                float h = acc[mf][nf][reg] + bhv[nf];
                h = fmaxf(h, 0.f);
                p += h * w2v[nf];
            }
            p += __shfl_xor(p, 1, 64);
            p += __shfl_xor(p, 2, 64);
            p += __shfl_xor(p, 4, 64);
            p += __shfl_xor(p, 8, 64);
            if (la == 0) red[wm * 64 + mf * 16 + lk * 4 + reg][wn] = p;
        }
    }
    __syncthreads();
    if (tid < 128)
        part[(size_t)(row0 + tid) * 2 + half] = red[tid][0] + red[tid][1] + red[tid][2] + red[tid][3];
}

// ---------------- K4: score + skip + marginal compaction ----------------
__global__ void score_kernel(const float* __restrict__ part, const float* __restrict__ b2,
                             const void* __restrict__ rare, const int* __restrict__ mode_p,
                             float* __restrict__ out, int* __restrict__ fixcnt,
                             int* __restrict__ fixlist) {
    int row = blockIdx.x * 256 + threadIdx.x;
    float logit = part[(size_t)row * 2] + part[(size_t)row * 2 + 1] + b2[0];
    float score = 1.f / (1.f + expf(-logit));
    int mode = *mode_p;
    bool rm = (mode == 1) ? (((const unsigned char*)rare)[row] != 0)
            : (mode == 2) ? (((const float*)rare)[row] != 0.f)
            : (((const int*)rare)[row] != 0);
    out[row] = ((score > 0.5f) && !rm) ? 1.f : 0.f;
    out[M_TOT + row] = score;
    if (fabsf(logit) < MARGIN) {
        int i = atomicAdd(fixcnt, 1);
        if (i < MAXFIX) fixlist[i] = row;
    }
}

// ---------------- K5: fixpost = fixup (all 256 blocks) + spin-sync + floor (blocks 0-7) ----------------
__global__ __launch_bounds__(512) void fixpost_kernel(
    const int* __restrict__ fixcnt, const int* __restrict__ fixlist,
    const float* __restrict__ tokens, const float* __restrict__ w1,
    const float* __restrict__ base_h, const float* __restrict__ w2,
    const float* __restrict__ b2, const void* __restrict__ rare,
    const int* __restrict__ mode_p, float* __restrict__ out,
    int* __restrict__ syncB) {
    __shared__ float tok[DD];
    __shared__ float part4[4][H1];
    __shared__ float red[8];
    __shared__ float s[NN];
    __shared__ unsigned char fl[NN];
    __shared__ int scnt;
    int tid = threadIdx.x;
    int lane = tid & 63, wid = tid >> 6;
    int ks = tid >> 7;
    int cg = tid & 127;
    int n = *fixcnt;
    if (n > MAXFIX) n = MAXFIX;
    for (int g = blockIdx.x; g < n; g += gridDim.x) {
        int row = fixlist[g];
        int b = row >> 12;
        if (tid < 256)
            ((float4*)tok)[tid] = ((const float4*)(tokens + (size_t)row * DD))[tid];
        __syncthreads();
        const float* wbase = w1 + (size_t)(ks * 256) * H1 + cg * 4;
        const float* tbase = tok + ks * 256;
        float4 a = {0.f, 0.f, 0.f, 0.f};
        #pragma unroll 8
        for (int k = 0; k < 256; ++k) {
            float4 w = *(const float4*)(wbase + (size_t)k * H1);
            float tv = tbase[k];
            a.x += tv * w.x; a.y += tv * w.y; a.z += tv * w.z; a.w += tv * w.w;
        }
        *(float4*)&part4[ks][cg * 4] = a;
        __syncthreads();
        float h = part4[0][tid] + part4[1][tid] + part4[2][tid] + part4[3][tid]
                + base_h[b * H1 + tid];
        h = fmaxf(h, 0.f);
        float p = h * w2[tid];
        p += __shfl_xor(p, 1, 64);
        p += __shfl_xor(p, 2, 64);
        p += __shfl_xor(p, 4, 64);
        p += __shfl_xor(p, 8, 64);
        p += __shfl_xor(p, 16, 64);
        p += __shfl_xor(p, 32, 64);
        if (lane == 0) red[wid] = p;
        __syncthreads();
        if (tid == 0) {
            float logit = b2[0];
            #pragma unroll
            for (int w = 0; w < 8; ++w) logit += red[w];
            float score = 1.f / (1.f + expf(-logit));
            int mode = *mode_p;
            bool rm = (mode == 1) ? (((const unsigned char*)rare)[row] != 0)
                    : (mode == 2) ? (((const float*)rare)[row] != 0.f)
                    : (((const int*)rare)[row] != 0);
            out[row] = ((score > 0.5f) && !rm) ? 1.f : 0.f;
            out[M_TOT + row] = score;
        }
        __syncthreads();
    }
    // arrive (release)
    __threadfence();
    __syncthreads();
    if (tid == 0) atomicAdd(syncB, 1);
    // floor on blocks 0-7 after all 256 arrived
    if (blockIdx.x < 8) {
        if (tid == 0) {
            while (atomicAdd(syncB, 0) < 256) __builtin_amdgcn_s_sleep(8);
        }
        __syncthreads();
        __threadfence();
        int b = blockIdx.x;
        if (tid == 0) scnt = 0;
        __syncthreads();
        int local = 0;
        for (int i = tid; i < NN; i += 512) {
            s[i] = out[M_TOT + b * NN + i];
            unsigned char sk = out[b * NN + i] > 0.5f;
            fl[i] = sk;
            local += sk;
        }
        atomicAdd(&scnt, local);
        __syncthreads();
        int deficit = scnt - (NN - MIN_ACTIVE);
        if (deficit <= 0) return;
        for (int i = tid; i < NN; i += 512) {
            if (!fl[i]) continue;
            float si = s[i];
            int rank = 0;
            for (int j = 0; j < NN; ++j) {
                if (fl[j] && (s[j] < si || (s[j] == si && j < i))) {
                    if (++rank >= deficit) break;
                }
            }
            if (rank < deficit) out[b * NN + i] = 0.f;
        }
    }
}

extern "C" void kernel_launch(void* const* d_in, const int* in_sizes, int n_in,
                              void* d_out, int out_size, void* d_ws, size_t ws_size,
                              hipStream_t stream) {
    const float* tokens   = (const float*)d_in[0];
    const float* ctx_C    = (const float*)d_in[1];
    const int*   t        = (const int*)d_in[2];
    const void*  rare     = d_in[3];
    const float* ctx_w    = (const float*)d_in[4];
    const float* ctx_b    = (const float*)d_in[5];
    const float* t_proj_w = (const float*)d_in[6];
    const float* t_proj_b = (const float*)d_in[7];
    const float* w1       = (const float*)d_in[8];
    const float* b1       = (const float*)d_in[9];
    const float* w2       = (const float*)d_in[10];
    const float* b2       = (const float*)d_in[11];
    float* out = (float*)d_out;

    char* ws = (char*)d_ws;
    unsigned short* w1tt  = (unsigned short*)(ws);                 // 1,048,576 B
    float* pmean          = (float*)(ws + 1048576);                // 262,144 B
    float* part           = (float*)(ws + 1310720);                // 262,144 B
    float* ctx_bn         = (float*)(ws + 1572864);                // 8,192 B
    float* t_emb          = (float*)(ws + 1581056);                // 32,768 B
    float* base_h         = (float*)(ws + 1613824);                // 16,384 B
    int*   mode           = (int*)  (ws + 1630208);                // 4 B
    int*   fixcnt         = (int*)  (ws + 1630272);                // 4 B
    int*   syncA          = (int*)  (ws + 1630336);                // 4 B
    int*   syncB          = (int*)  (ws + 1630400);                // 4 B
    int*   fixlist        = (int*)  (ws + 1630464);                // 32,768 B

    pre1_kernel<<<512, 256, 0, stream>>>(w1, w1tt, ctx_C, pmean,
                                         (const unsigned char*)rare, mode, fixcnt, syncA, syncB);
    pre2_kernel<<<192, 256, 0, stream>>>(pmean, t, ctx_w, ctx_b, t_proj_w, t_proj_b,
                                         w1, b1, ctx_bn, t_emb, base_h, syncA);
    gemm_kernel<<<dim3(256, 2), 512, 0, stream>>>(tokens, w1tt, base_h, w2, part);
    score_kernel<<<128, 256, 0, stream>>>(part, b2, rare, mode, out, fixcnt, fixlist);
    fixpost_kernel<<<256, 512, 0, stream>>>(fixcnt, fixlist, tokens, w1, base_h, w2,
                                            b2, rare, mode, out, syncB);
}

// Round 13
// 174.911 us; speedup vs baseline: 1.4648x; 1.3432x over previous
//
#include <hip/hip_runtime.h>
#include <math.h>

#define NN 4096
#define DD 1024
#define M_TOT 32768
#define H1 512
#define MIN_ACTIVE 819
#define MARGIN 0.03f
#define MAXFIX 8192

typedef __bf16 bf16x8 __attribute__((ext_vector_type(8)));
typedef float f32x4 __attribute__((ext_vector_type(4)));

__device__ __forceinline__ unsigned short f2bf(float f) {
    unsigned int u = __float_as_uint(f);
    return (unsigned short)((u + 0x7FFFu + ((u >> 16) & 1u)) >> 16);
}

__device__ __forceinline__ void glds16(const unsigned short* g, unsigned short* l) {
    __builtin_amdgcn_global_load_lds(
        (const __attribute__((address_space(1))) unsigned int*)g,
        (__attribute__((address_space(3))) unsigned int*)l, 16, 0, 0);
}

// ---------------- K1: fused convB (blocks 0-255) + pmean (blocks 256-511) ----------------
__global__ void convB_pmean_kernel(const float* __restrict__ w1, unsigned short* __restrict__ w1tt,
                                   const float* __restrict__ ctx, float* __restrict__ pmean,
                                   const unsigned char* __restrict__ rare, int* __restrict__ mode,
                                   int* __restrict__ fixcnt) {
    __shared__ float tile[32][65];
    __shared__ int nonbin, oneoff;
    int blk = blockIdx.x;
    int tid = threadIdx.x;
    if (blk < 256) {
        int t = blk >> 3;            // k-tile 0..31
        int c0 = (blk & 7) * 64;     // col group
        #pragma unroll
        for (int i = 0; i < 8; ++i) {
            int idx = tid + 256 * i; // 0..2047
            int kk = idx >> 6, cc = idx & 63;
            tile[kk][cc] = w1[(size_t)(t * 32 + kk) * H1 + c0 + cc];
        }
        __syncthreads();
        {
            int cc = tid >> 2, jp = tid & 3;
            int c = c0 + cc;
            int j = jp ^ ((c >> 1) & 3);
            unsigned int w[4];
            #pragma unroll
            for (int q = 0; q < 4; ++q)
                w[q] = (unsigned int)f2bf(tile[j * 8 + 2 * q][cc])
                     | ((unsigned int)f2bf(tile[j * 8 + 2 * q + 1][cc]) << 16);
            uint4 v; v.x = w[0]; v.y = w[1]; v.z = w[2]; v.w = w[3];
            *(uint4*)(w1tt + ((size_t)t * 512 + c) * 32 + jp * 8) = v;
        }
        if (blk == 0) {
            if (tid == 0) { nonbin = 0; oneoff = 0; *fixcnt = 0; }
            __syncthreads();
            int lnon = 0, lone = 0;
            for (int i = tid; i < 32768; i += 256) {
                unsigned char b = rare[i];
                if (b > 1) lnon = 1;
                else if (b == 1 && (i & 3) != 0) lone = 1;
            }
            if (lnon) atomicOr(&nonbin, 1);
            if (lone) atomicOr(&oneoff, 1);
            __syncthreads();
            if (tid == 0) *mode = nonbin ? 2 : (oneoff ? 1 : 0);
        }
    } else {
        int pblk = blk - 256;        // 256 = 8b * 4dq * 8nz
        int b = pblk >> 5, dq = (pblk >> 3) & 3, nz = pblk & 7;
        int d = dq * 256 + tid;
        const float* base = ctx + ((size_t)(b * 512 + nz * 64)) * DD + d;
        float acc = 0.f;
        for (int n = 0; n < 64; ++n) acc += base[(size_t)n * DD];
        pmean[(b * 8 + nz) * DD + d] = acc;
    }
}

// ---------------- K2: midk (prep fused): blocks 0-63 ctx_bn, 64-191 t_emb ----------------
__global__ __launch_bounds__(256) void midk_kernel(
    const float* __restrict__ pmean, const int* __restrict__ t,
    const float* __restrict__ ctx_w, const float* __restrict__ ctx_b,
    const float* __restrict__ tpw, const float* __restrict__ tpb,
    float* __restrict__ ctx_bn, float* __restrict__ t_emb) {
    __shared__ float sh[1024];
    __shared__ float red8[8][32];
    __shared__ float red4[4][64];
    int tid = threadIdx.x;
    if (blockIdx.x < 64) {
        int b = blockIdx.x >> 3, cg = blockIdx.x & 7;
        for (int j = tid; j < 1024; j += 256) {
            float s = 0.f;
            #pragma unroll
            for (int nz = 0; nz < 8; ++nz) s += pmean[(b * 8 + nz) * DD + j];
            sh[j] = s * (1.f / 512.f);
        }
        __syncthreads();
        int c = cg * 32 + (tid & 31), ks = tid >> 5;
        const float* mb = sh + ks * 128;
        const float* wb = ctx_w + (size_t)(ks * 128) * 256 + c;
        float acc = 0.f;
        for (int i = 0; i < 128; ++i) acc += mb[i] * wb[(size_t)i * 256];
        red8[ks][tid & 31] = acc;
        __syncthreads();
        if (tid < 32) {
            float s = 0.f;
            for (int k = 0; k < 8; ++k) s += red8[k][tid];
            ctx_bn[b * 256 + cg * 32 + tid] = s + ctx_b[cg * 32 + tid];
        }
    } else {
        int blk = blockIdx.x - 64;
        int b = blk >> 4, cg = blk & 15;
        double tv = (double)t[b];
        const double neg_ln = -log(10000.0) / 511.0;
        for (int j = tid; j < 1024; j += 256) {
            int jj = j & 511;
            double arg = tv * exp(neg_ln * (double)jj);
            sh[j] = (float)((j < 512) ? sin(arg) : cos(arg));
        }
        __syncthreads();
        int c = cg * 64 + (tid & 63), ks = tid >> 6;
        const float* eb = sh + ks * 256;
        const float* wb = tpw + (size_t)(ks * 256) * DD + c;
        float acc = 0.f;
        for (int i = 0; i < 256; ++i) acc += eb[i] * wb[(size_t)i * DD];
        red4[ks][tid & 63] = acc;
        __syncthreads();
        if (tid < 64) {
            float s = red4[0][tid] + red4[1][tid] + red4[2][tid] + red4[3][tid];
            t_emb[b * DD + cg * 64 + tid] = s + tpb[cg * 64 + tid];
        }
    }
}

// ---------------- K3: base_h ----------------
__global__ void baseh_kernel(const float* __restrict__ ctx_bn, const float* __restrict__ t_emb,
                             const float* __restrict__ w1, const float* __restrict__ b1,
                             float* __restrict__ base_h) {
    __shared__ float red[8][32];
    int b = blockIdx.x, cg = blockIdx.y;
    int c = cg * 32 + (threadIdx.x & 31), ks = threadIdx.x >> 5;
    float acc = 0.f;
    for (int i = 0; i < 160; ++i) {
        int k = ks * 160 + i;
        float v = (k < 256) ? ctx_bn[b * 256 + k] : t_emb[b * DD + k - 256];
        acc += v * w1[(size_t)(1024 + k) * H1 + c];
    }
    red[ks][threadIdx.x & 31] = acc;
    __syncthreads();
    if (threadIdx.x < 32) {
        float s = 0.f;
        for (int k = 0; k < 8; ++k) s += red[k][threadIdx.x];
        base_h[b * H1 + cg * 32 + threadIdx.x] = s + b1[cg * 32 + threadIdx.x];
    }
}

// ---------------- K4: MFMA GEMM (r8 best config: dbuf A+B, single barrier + counted vmcnt) ----------------
__global__ __launch_bounds__(512, 4) void gemm_kernel(
    const float* __restrict__ tokens, const unsigned short* __restrict__ w1tt,
    const float* __restrict__ baseh, const float* __restrict__ w2,
    float* __restrict__ part) {
    __shared__ unsigned short As[2][128 * 40];   // padded stride 40
    __shared__ unsigned short Bs[2][256 * 32];   // linear (glds dest), swizzled content
    __shared__ float red[128][4];
    int tid = threadIdx.x;
    int lane = tid & 63, wid = tid >> 6;
    int wm = wid >> 2, wn = wid & 3;             // wave = 64 rows x 64 cols
    int la = lane & 15, lk = lane >> 4;
    int row0 = blockIdx.x * 128;
    int half = blockIdx.y;
    const unsigned short* wsrc = w1tt + (size_t)half * 256 * 32;

    f32x4 acc[4][4];
    #pragma unroll
    for (int i = 0; i < 4; ++i)
        #pragma unroll
        for (int j = 0; j < 4; ++j)
            acc[i][j] = (f32x4){0.f, 0.f, 0.f, 0.f};

    float4 sa[2];
    #define LOAD_A(kt_) { \
        _Pragma("unroll") \
        for (int i = 0; i < 2; ++i) { \
            int id = tid + 512 * i; \
            int r = id >> 3, xk = id & 7; \
            sa[i] = *(const float4*)(tokens + (size_t)(row0 + r) * DD + (kt_) + xk * 4); \
        } }
    #define WRITE_A(bb_) { \
        _Pragma("unroll") \
        for (int i = 0; i < 2; ++i) { \
            int id = tid + 512 * i; \
            int r = id >> 3, xk = id & 7; \
            ushort4 h; \
            h.x = f2bf(sa[i].x); h.y = f2bf(sa[i].y); \
            h.z = f2bf(sa[i].z); h.w = f2bf(sa[i].w); \
            *(ushort4*)(&As[bb_][r * 40 + xk * 4]) = h; \
        } }
    #define STAGE_B(t_, bb_) { \
        const unsigned short* gsrc = wsrc + (size_t)(t_) * 512 * 32; \
        _Pragma("unroll") \
        for (int q = 0; q < 2; ++q) { \
            int chunk = wid * 2 + q; \
            glds16(gsrc + chunk * 512 + lane * 8, &Bs[bb_][chunk * 512]); \
        } }

    // prologue: B(0) glds, A(0) regs->LDS (drains all), A(1) prefetch
    STAGE_B(0, 0);
    LOAD_A(0);
    WRITE_A(0);                       // compiler inserts vmcnt for sa deps (drains glds too)
    LOAD_A(32);
    asm volatile("s_waitcnt lgkmcnt(0)" ::: "memory");
    __builtin_amdgcn_s_barrier();
    __builtin_amdgcn_sched_barrier(0);

    for (int t = 0; t < 32; ++t) {
        int bb = t & 1;
        // frag reads of step t
        bf16x8 af[4], bfr[4];
        #pragma unroll
        for (int mf = 0; mf < 4; ++mf) {
            int r = wm * 64 + mf * 16 + la;
            af[mf] = *(const bf16x8*)(&As[bb][r * 40 + lk * 8]);
        }
        #pragma unroll
        for (int nf = 0; nf < 4; ++nf) {
            int c = wn * 64 + nf * 16 + la;
            int sw = lk ^ ((c >> 1) & 3);
            bfr[nf] = *(const bf16x8*)(&Bs[bb][c * 32 + sw * 8]);
        }
        if (t < 31) {
            WRITE_A(bb ^ 1);               // A(t+1): regs loaded last iter (vmcnt auto)
            STAGE_B(t + 1, bb ^ 1);        // 2 glds/wave
            __builtin_amdgcn_sched_barrier(0);  // pin: glds issue before A prefetch
            if (t < 30) LOAD_A((t + 2) * 32);   // stays in flight across barrier
        }
        #pragma unroll
        for (int mf = 0; mf < 4; ++mf)
            #pragma unroll
            for (int nf = 0; nf < 4; ++nf)
                acc[mf][nf] = __builtin_amdgcn_mfma_f32_16x16x32_bf16(af[mf], bfr[nf], acc[mf][nf], 0, 0, 0);
        if (t < 31) {
            if (t < 30) asm volatile("s_waitcnt vmcnt(2)" ::: "memory");  // B glds done; A loads in flight
            else        asm volatile("s_waitcnt vmcnt(0)" ::: "memory");
            asm volatile("s_waitcnt lgkmcnt(0)" ::: "memory");            // A ds_writes visible
            __builtin_amdgcn_s_barrier();
            __builtin_amdgcn_sched_barrier(0);
        }
    }
    #undef LOAD_A
    #undef WRITE_A
    #undef STAGE_B

    // epilogue: h = acc + baseh[col]; relu; * w2[col]; row-reduce -> per-half partial
    int b = row0 >> 12;
    const float* bh = baseh + b * H1;
    float bhv[4], w2v[4];
    #pragma unroll
    for (int nf = 0; nf < 4; ++nf) {
        int col = half * 256 + wn * 64 + nf * 16 + la;
        bhv[nf] = bh[col];
        w2v[nf] = w2[col];
    }
    #pragma unroll
    for (int mf = 0; mf < 4; ++mf) {
        #pragma unroll
        for (int reg = 0; reg < 4; ++reg) {
            float p = 0.f;
            #pragma unroll
            for (int nf = 0; nf < 4; ++nf) {
                float h = acc[mf][nf][reg] + bhv[nf];
                h = fmaxf(h, 0.f);
                p += h * w2v[nf];
            }
            p += __shfl_xor(p, 1, 64);
            p += __shfl_xor(p, 2, 64);
            p += __shfl_xor(p, 4, 64);
            p += __shfl_xor(p, 8, 64);
            if (la == 0) red[wm * 64 + mf * 16 + lk * 4 + reg][wn] = p;
        }
    }
    __syncthreads();
    if (tid < 128)
        part[(size_t)(row0 + tid) * 2 + half] = red[tid][0] + red[tid][1] + red[tid][2] + red[tid][3];
}

// ---------------- K5: score + skip + marginal compaction ----------------
__global__ void score_kernel(const float* __restrict__ part, const float* __restrict__ b2,
                             const void* __restrict__ rare, const int* __restrict__ mode_p,
                             float* __restrict__ out, int* __restrict__ fixcnt,
                             int* __restrict__ fixlist) {
    int row = blockIdx.x * 256 + threadIdx.x;
    float logit = part[(size_t)row * 2] + part[(size_t)row * 2 + 1] + b2[0];
    float score = 1.f / (1.f + expf(-logit));
    int mode = *mode_p;
    bool rm = (mode == 1) ? (((const unsigned char*)rare)[row] != 0)
            : (mode == 2) ? (((const float*)rare)[row] != 0.f)
            : (((const int*)rare)[row] != 0);
    out[row] = ((score > 0.5f) && !rm) ? 1.f : 0.f;
    out[M_TOT + row] = score;
    if (fabsf(logit) < MARGIN) {
        int i = atomicAdd(fixcnt, 1);
        if (i < MAXFIX) fixlist[i] = row;
    }
}

// ---------------- K6: exact f32 recompute, 1 row/block, 4-way k-split x float4 cols ----------------
__global__ __launch_bounds__(512) void fixup_kernel(
    const int* __restrict__ fixcnt, const int* __restrict__ fixlist,
    const float* __restrict__ tokens, const float* __restrict__ w1,
    const float* __restrict__ base_h, const float* __restrict__ w2,
    const float* __restrict__ b2, const void* __restrict__ rare,
    const int* __restrict__ mode_p, float* __restrict__ out) {
    __shared__ float tok[DD];
    __shared__ float part4[4][H1];   // k-quarter partials per col
    __shared__ float red[8];
    int tid = threadIdx.x;
    int lane = tid & 63, wid = tid >> 6;
    int ks = tid >> 7;               // k-quarter 0..3 (256 k each)
    int cg = tid & 127;              // col group: cols 4cg..4cg+3
    int n = *fixcnt;
    if (n > MAXFIX) n = MAXFIX;
    for (int g = blockIdx.x; g < n; g += gridDim.x) {
        int row = fixlist[g];
        int b = row >> 12;
        if (tid < 256)
            ((float4*)tok)[tid] = ((const float4*)(tokens + (size_t)row * DD))[tid];
        __syncthreads();
        const float* wbase = w1 + (size_t)(ks * 256) * H1 + cg * 4;
        const float* tbase = tok + ks * 256;
        float4 a = {0.f, 0.f, 0.f, 0.f};
        #pragma unroll 8
        for (int k = 0; k < 256; ++k) {
            float4 w = *(const float4*)(wbase + (size_t)k * H1);
            float tv = tbase[k];
            a.x += tv * w.x; a.y += tv * w.y; a.z += tv * w.z; a.w += tv * w.w;
        }
        *(float4*)&part4[ks][cg * 4] = a;
        __syncthreads();
        float h = part4[0][tid] + part4[1][tid] + part4[2][tid] + part4[3][tid]
                + base_h[b * H1 + tid];
        h = fmaxf(h, 0.f);
        float p = h * w2[tid];
        p += __shfl_xor(p, 1, 64);
        p += __shfl_xor(p, 2, 64);
        p += __shfl_xor(p, 4, 64);
        p += __shfl_xor(p, 8, 64);
        p += __shfl_xor(p, 16, 64);
        p += __shfl_xor(p, 32, 64);
        if (lane == 0) red[wid] = p;
        __syncthreads();
        if (tid == 0) {
            float logit = b2[0];
            #pragma unroll
            for (int w = 0; w < 8; ++w) logit += red[w];
            float score = 1.f / (1.f + expf(-logit));
            int mode = *mode_p;
            bool rm = (mode == 1) ? (((const unsigned char*)rare)[row] != 0)
                    : (mode == 2) ? (((const float*)rare)[row] != 0.f)
                    : (((const int*)rare)[row] != 0);
            out[row] = ((score > 0.5f) && !rm) ? 1.f : 0.f;
            out[M_TOT + row] = score;
        }
        __syncthreads();
    }
}

// ---------------- K7: 20% active-floor correction ----------------
__global__ void floor_kernel(float* __restrict__ out) {
    __shared__ float s[NN];
    __shared__ unsigned char f[NN];
    __shared__ int cnt;
    int b = blockIdx.x, tid = threadIdx.x;
    if (tid == 0) cnt = 0;
    __syncthreads();
    int local = 0;
    for (int i = tid; i < NN; i += 256) {
        s[i] = out[M_TOT + b * NN + i];
        unsigned char sk = out[b * NN + i] > 0.5f;
        f[i] = sk;
        local += sk;
    }
    atomicAdd(&cnt, local);
    __syncthreads();
    int deficit = cnt - (NN - MIN_ACTIVE);
    if (deficit <= 0) return;
    for (int i = tid; i < NN; i += 256) {
        if (!f[i]) continue;
        float si = s[i];
        int rank = 0;
        for (int j = 0; j < NN; ++j) {
            if (f[j] && (s[j] < si || (s[j] == si && j < i))) {
                if (++rank >= deficit) break;
            }
        }
        if (rank < deficit) out[b * NN + i] = 0.f;
    }
}

extern "C" void kernel_launch(void* const* d_in, const int* in_sizes, int n_in,
                              void* d_out, int out_size, void* d_ws, size_t ws_size,
                              hipStream_t stream) {
    const float* tokens   = (const float*)d_in[0];
    const float* ctx_C    = (const float*)d_in[1];
    const int*   t        = (const int*)d_in[2];
    const void*  rare     = d_in[3];
    const float* ctx_w    = (const float*)d_in[4];
    const float* ctx_b    = (const float*)d_in[5];
    const float* t_proj_w = (const float*)d_in[6];
    const float* t_proj_b = (const float*)d_in[7];
    const float* w1       = (const float*)d_in[8];
    const float* b1       = (const float*)d_in[9];
    const float* w2       = (const float*)d_in[10];
    const float* b2       = (const float*)d_in[11];
    float* out = (float*)d_out;

    char* ws = (char*)d_ws;
    unsigned short* w1tt  = (unsigned short*)(ws);                 // 1,048,576 B (tiled+swizzled)
    float* pmean          = (float*)(ws + 1048576);                // 262,144 B
    float* part           = (float*)(ws + 1048576);                // alias: pmean dead before gemm
    float* ctx_bn         = (float*)(ws + 1376256);                // 8,192 B
    float* t_emb          = (float*)(ws + 1384448);                // 32,768 B
    float* base_h         = (float*)(ws + 1417216);                // 16,384 B
    int*   mode           = (int*)  (ws + 1433600);                // 4 B
    int*   fixcnt         = (int*)  (ws + 1433664);                // 4 B
    int*   fixlist        = (int*)  (ws + 1433728);                // 32,768 B

    convB_pmean_kernel<<<512, 256, 0, stream>>>(w1, w1tt, ctx_C, pmean,
                                                (const unsigned char*)rare, mode, fixcnt);
    midk_kernel<<<192, 256, 0, stream>>>(pmean, t, ctx_w, ctx_b, t_proj_w, t_proj_b, ctx_bn, t_emb);
    baseh_kernel<<<dim3(8, 16), 256, 0, stream>>>(ctx_bn, t_emb, w1, b1, base_h);
    gemm_kernel<<<dim3(256, 2), 512, 0, stream>>>(tokens, w1tt, base_h, w2, part);
    score_kernel<<<128, 256, 0, stream>>>(part, b2, rare, mode, out, fixcnt, fixlist);
    fixup_kernel<<<512, 512, 0, stream>>>(fixcnt, fixlist, tokens, w1, base_h, w2, b2, rare, mode, out);
    floor_kernel<<<8, 256, 0, stream>>>(out);
}